// Round 4
// baseline (25.705 us; speedup 1.0000x reference)
//
#include <hip/hip_runtime.h>

#define K_TERMS 32   // ||B||inf * w_max <= ~6.6 -> tail 6.6^32/32! ~ 7e-10 rel

// ws layout: [0] double acc | [8] uint tickets | [64..] 33 floats coef+c
//
// 2-node graph:
//  1) pt_setup: ONE wave; EVERY lane redundantly computes all 32 series
//     coefficients d_k = (alpha^T B^k s)/k! with B = S + cI held entirely
//     in registers (64 FMAs/iter, 8 independent depth-8 chains -> ILP,
//     ZERO cross-lane ops). B >= 0 entrywise -> no cancellation -> fp32 ok.
//     Lane 0 writes coefs and zeroes acc + tickets.
//  2) pt_score: grid-stride Horner + __logf; block partial -> fp64 atomicAdd;
//     last block (ticket) reads acc via device-scope RMW and writes out.

__global__ void pt_setup_kernel(const float* __restrict__ S,
                                const float* __restrict__ alpha,
                                float* __restrict__ coef_c,
                                double* __restrict__ acc,
                                unsigned* __restrict__ tickets) {
    float Sm[64];
#pragma unroll
    for (int i = 0; i < 64; ++i) Sm[i] = S[i];      // uniform -> s_load
    float al[8];
#pragma unroll
    for (int i = 0; i < 8; ++i) al[i] = alpha[i];

    float c = 0.0f;                                  // c = max_i(-S_ii)
#pragma unroll
    for (int i = 0; i < 8; ++i) c = fmaxf(c, -Sm[i * 8 + i]);

    float B[64];
#pragma unroll
    for (int i = 0; i < 8; ++i)
#pragma unroll
        for (int j = 0; j < 8; ++j)
            B[i * 8 + j] = Sm[i * 8 + j] + ((i == j) ? c : 0.0f);  // >= 0

    float v[8];
#pragma unroll
    for (int i = 0; i < 8; ++i) {                    // s_i = -sum_j S_ij > 0
        float rs = 0.0f;
#pragma unroll
        for (int j = 0; j < 8; ++j) rs += Sm[i * 8 + j];
        v[i] = -rs;
    }

    float coef[K_TERMS];
    {
        float d = 0.0f;
#pragma unroll
        for (int j = 0; j < 8; ++j) d = fmaf(al[j], v[j], d);
        coef[0] = d;
    }
#pragma unroll
    for (int k = 1; k < K_TERMS; ++k) {
        float nv[8];
#pragma unroll
        for (int i = 0; i < 8; ++i) {                // 8 independent chains
            float m = 0.0f;
#pragma unroll
            for (int j = 0; j < 8; ++j) m = fmaf(B[i * 8 + j], v[j], m);
            nv[i] = m * (1.0f / (float)k);           // const after unroll
        }
#pragma unroll
        for (int i = 0; i < 8; ++i) v[i] = nv[i];
        float d = 0.0f;
#pragma unroll
        for (int j = 0; j < 8; ++j) d = fmaf(al[j], v[j], d);
        coef[k] = d;
    }

    if (threadIdx.x == 0) {
#pragma unroll
        for (int k = 0; k < K_TERMS; ++k) coef_c[k] = coef[k];
        coef_c[K_TERMS] = c;
        *acc = 0.0;
        *tickets = 0u;
    }
}

__device__ __forceinline__ float pt_logdens(float x, const float* coef, float c) {
    float p = coef[K_TERMS - 1];
#pragma unroll
    for (int k = K_TERMS - 2; k >= 0; --k) p = fmaf(p, x, coef[k]);
    return __logf(p) - c * x;                        // p > 0 always
}

__global__ __launch_bounds__(256) void pt_score_kernel(
    const float* __restrict__ w, int n,
    const float* __restrict__ coef_c,
    double* __restrict__ acc,
    unsigned* __restrict__ tickets,
    float* __restrict__ out)
{
    float coef[K_TERMS];
#pragma unroll
    for (int k = 0; k < K_TERMS; ++k) coef[k] = coef_c[k];  // uniform -> SGPR
    const float c = coef_c[K_TERMS];

    double local = 0.0;
    const int tid = blockIdx.x * blockDim.x + threadIdx.x;
    const int nthreads = gridDim.x * blockDim.x;
    const int n4 = n >> 2;
    const float4* w4 = (const float4*)w;
    for (int i = tid; i < n4; i += nthreads) {
        float4 wv = w4[i];
        float a4 = pt_logdens(wv.x, coef, c);
        a4 += pt_logdens(wv.y, coef, c);
        a4 += pt_logdens(wv.z, coef, c);
        a4 += pt_logdens(wv.w, coef, c);
        local += (double)a4;
    }
    for (int i = (n4 << 2) + tid; i < n; i += nthreads)     // n % 4 tail
        local += (double)pt_logdens(w[i], coef, c);

#pragma unroll
    for (int off = 32; off > 0; off >>= 1)
        local += __shfl_down(local, off, 64);

    __shared__ double red[4];
    const int wid = threadIdx.x >> 6;
    const int lane = threadIdx.x & 63;
    if (lane == 0) red[wid] = local;
    __syncthreads();

    if (threadIdx.x == 0) {
        double part = red[0] + red[1] + red[2] + red[3];
        atomicAdd(acc, part);                // device-scope fp64 atomic
        __threadfence();
        unsigned t = atomicAdd(tickets, 1u);
        if (t == (unsigned)gridDim.x - 1u) { // last block: finalize
            double total = atomicAdd(acc, 0.0);   // RMW -> coherent read
            out[0] = (float)total;
        }
    }
}

extern "C" void kernel_launch(void* const* d_in, const int* in_sizes, int n_in,
                              void* d_out, int out_size, void* d_ws, size_t ws_size,
                              hipStream_t stream) {
    const float* w     = (const float*)d_in[0];   // [N_W]
    const float* S     = (const float*)d_in[1];   // [8,8]
    const float* alpha = (const float*)d_in[2];   // [8]
    float* out = (float*)d_out;

    double*   acc     = (double*)d_ws;
    unsigned* tickets = (unsigned*)((char*)d_ws + 8);
    float*    coef_c  = (float*)((char*)d_ws + 64);

    const int n = in_sizes[0];
    int n4 = n >> 2;
    int blocks = (n4 + 255) / 256;
    if (blocks < 1) blocks = 1;
    if (blocks > 2048) blocks = 2048;     // grid-stride handles the rest

    pt_setup_kernel<<<1, 64, 0, stream>>>(S, alpha, coef_c, acc, tickets);
    pt_score_kernel<<<blocks, 256, 0, stream>>>(w, n, coef_c, acc, tickets, out);
}

// Round 5
// 15.905 us; speedup vs baseline: 1.6161x; 1.6161x over previous
//
#include <hip/hip_runtime.h>

#define K_TERMS 32   // ||B||inf * w_max <= ~6.6 -> tail 6.6^32/32! ~ 7e-10 rel

// 3-node pipeline (all components individually measured-fast):
//  1) pt_setup [R4's register version, ~1.7us]: one wave, EVERY lane
//     redundantly computes coef_k = (alpha^T B^k s)/k! with B = S + cI held
//     entirely in registers (8 independent depth-8 FMA chains per iter, zero
//     cross-lane ops). B >= 0 entrywise -> zero-cancellation series -> fp32 ok.
//  2) pt_score [R3's exact kernel]: grid-stride Horner + __logf, uniform
//     coef loads (SGPR), one double partial per block. No atomics, no fences.
//  3) pt_reduce [R3's exact kernel]: one block sums partials, writes out.

__global__ void pt_setup_kernel(const float* __restrict__ S,
                                const float* __restrict__ alpha,
                                float* __restrict__ coef_c) {
    float Sm[64];
#pragma unroll
    for (int i = 0; i < 64; ++i) Sm[i] = S[i];      // uniform loads
    float al[8];
#pragma unroll
    for (int i = 0; i < 8; ++i) al[i] = alpha[i];

    float c = 0.0f;                                  // c = max_i(-S_ii)
#pragma unroll
    for (int i = 0; i < 8; ++i) c = fmaxf(c, -Sm[i * 8 + i]);

    float B[64];
#pragma unroll
    for (int i = 0; i < 8; ++i)
#pragma unroll
        for (int j = 0; j < 8; ++j)
            B[i * 8 + j] = Sm[i * 8 + j] + ((i == j) ? c : 0.0f);  // >= 0

    float v[8];
#pragma unroll
    for (int i = 0; i < 8; ++i) {                    // s_i = -sum_j S_ij > 0
        float rs = 0.0f;
#pragma unroll
        for (int j = 0; j < 8; ++j) rs += Sm[i * 8 + j];
        v[i] = -rs;
    }

    float coef[K_TERMS];
    {
        float d = 0.0f;
#pragma unroll
        for (int j = 0; j < 8; ++j) d = fmaf(al[j], v[j], d);
        coef[0] = d;
    }
#pragma unroll
    for (int k = 1; k < K_TERMS; ++k) {
        float nv[8];
#pragma unroll
        for (int i = 0; i < 8; ++i) {                // 8 independent chains
            float m = 0.0f;
#pragma unroll
            for (int j = 0; j < 8; ++j) m = fmaf(B[i * 8 + j], v[j], m);
            nv[i] = m * (1.0f / (float)k);           // const after unroll
        }
#pragma unroll
        for (int i = 0; i < 8; ++i) v[i] = nv[i];
        float d = 0.0f;
#pragma unroll
        for (int j = 0; j < 8; ++j) d = fmaf(al[j], v[j], d);
        coef[k] = d;
    }

    if (threadIdx.x == 0) {
#pragma unroll
        for (int k = 0; k < K_TERMS; ++k) coef_c[k] = coef[k];
        coef_c[K_TERMS] = c;
    }
}

__device__ __forceinline__ float pt_logdens(float x, const float* coef, float c) {
    float p = coef[K_TERMS - 1];
#pragma unroll
    for (int k = K_TERMS - 2; k >= 0; --k) p = fmaf(p, x, coef[k]);
    return __logf(p) - c * x;                        // p > 0 always
}

__global__ __launch_bounds__(256) void pt_score_kernel(
    const float* __restrict__ w, int n,
    const float* __restrict__ coef_c,
    double* __restrict__ partials)
{
    float coef[K_TERMS];
#pragma unroll
    for (int k = 0; k < K_TERMS; ++k) coef[k] = coef_c[k];  // uniform -> SGPR
    const float c = coef_c[K_TERMS];

    double local = 0.0;
    const int tid = blockIdx.x * blockDim.x + threadIdx.x;
    const int nthreads = gridDim.x * blockDim.x;
    const int n4 = n >> 2;
    const float4* w4 = (const float4*)w;
    for (int i = tid; i < n4; i += nthreads) {
        float4 wv = w4[i];
        float a4 = pt_logdens(wv.x, coef, c);
        a4 += pt_logdens(wv.y, coef, c);
        a4 += pt_logdens(wv.z, coef, c);
        a4 += pt_logdens(wv.w, coef, c);
        local += (double)a4;
    }
    for (int i = (n4 << 2) + tid; i < n; i += nthreads)     // n % 4 tail
        local += (double)pt_logdens(w[i], coef, c);

#pragma unroll
    for (int off = 32; off > 0; off >>= 1)
        local += __shfl_down(local, off, 64);

    __shared__ double red[4];
    const int wid = threadIdx.x >> 6;
    const int lane = threadIdx.x & 63;
    if (lane == 0) red[wid] = local;
    __syncthreads();
    if (threadIdx.x == 0)
        partials[blockIdx.x] = red[0] + red[1] + red[2] + red[3];
}

__global__ __launch_bounds__(512) void pt_reduce_kernel(
    const double* __restrict__ partials, int nparts, float* __restrict__ out)
{
    double local = 0.0;
    for (int i = threadIdx.x; i < nparts; i += 512) local += partials[i];
#pragma unroll
    for (int off = 32; off > 0; off >>= 1)
        local += __shfl_down(local, off, 64);

    __shared__ double red[8];
    const int wid = threadIdx.x >> 6;
    const int lane = threadIdx.x & 63;
    if (lane == 0) red[wid] = local;
    __syncthreads();
    if (threadIdx.x == 0) {
        double t = 0.0;
#pragma unroll
        for (int i = 0; i < 8; ++i) t += red[i];
        out[0] = (float)t;
    }
}

extern "C" void kernel_launch(void* const* d_in, const int* in_sizes, int n_in,
                              void* d_out, int out_size, void* d_ws, size_t ws_size,
                              hipStream_t stream) {
    const float* w     = (const float*)d_in[0];   // [N_W]
    const float* S     = (const float*)d_in[1];   // [8,8]
    const float* alpha = (const float*)d_in[2];   // [8]
    float* out = (float*)d_out;

    float*  coef_c   = (float*)d_ws;                       // 33 floats
    double* partials = (double*)((char*)d_ws + 256);

    const int n = in_sizes[0];
    int n4 = n >> 2;
    int blocks = (n4 + 255) / 256;
    if (blocks < 1) blocks = 1;
    if (blocks > 2048) blocks = 2048;     // grid-stride handles the rest

    pt_setup_kernel<<<1, 64, 0, stream>>>(S, alpha, coef_c);
    pt_score_kernel<<<blocks, 256, 0, stream>>>(w, n, coef_c, partials);
    pt_reduce_kernel<<<1, 512, 0, stream>>>(partials, blocks, out);
}